// Round 1
// baseline (228.005 us; speedup 1.0000x reference)
//
#include <hip/hip_runtime.h>
#include <hip/hip_bf16.h>
#include <math.h>

// ---------------------------------------------------------------------------
// Metric loss (lifted structure, Song et al.) on MI355X.
//   loss = metric(text[4096,256]) + metric(emb[8192,256])
// Core cost: two Gram matrices -> bf16 MFMA (16x16x32), fused epilogue
// computing E=exp(1-D) row sums (pair-block-masked) + atomic row accumulate.
// Duplicate rows in emb (shape[s] at rows 2s+1 and 4096+2s) are special-cased
// to E=e exactly (D=0 in the fp32 reference) to kill the dominant error term.
// sq[] is computed FROM THE bf16-ROUNDED values so D^2 = sq_i+sq_j-2G stays
// consistent; per-pair distances D[2p,2p+1] are computed in exact fp32.
// ---------------------------------------------------------------------------

typedef __bf16 bf16x8 __attribute__((ext_vector_type(8)));
typedef float floatx4 __attribute__((ext_vector_type(4)));

#define KD 256
#define N_TT 4096
#define N_ST 8192
#define P_TT 2048
#define P_ST 4096
#define BM 128
#define BN 128
#define BK 32

__device__ __forceinline__ void gload_lds16(const void* g, void* l) {
  // async global->LDS, 16B per lane; LDS dest = wave-uniform base + lane*16
  __builtin_amdgcn_global_load_lds((const __attribute__((address_space(1))) unsigned int*)g,
                                   (__attribute__((address_space(3))) unsigned int*)l,
                                   16, 0, 0);
}

// ---- prep: bf16 convert text, build emb (bf16), row sq from bf16 values ----
__global__ __launch_bounds__(256) void prep_kernel(const float* __restrict__ text,
                                                   const float* __restrict__ shape,
                                                   __bf16* __restrict__ xtt,
                                                   __bf16* __restrict__ emb,
                                                   float* __restrict__ sq_tt,
                                                   float* __restrict__ sq_st) {
  int wave = (blockIdx.x * 256 + threadIdx.x) >> 6;  // one wave per output row
  int lane = threadIdx.x & 63;
  const float* src;
  __bf16* dst;
  float* sqp;
  if (wave < N_TT) {
    src = text + (size_t)wave * KD;
    dst = xtt + (size_t)wave * KD;
    sqp = sq_tt + wave;
  } else {
    int g = wave - N_TT;
    if (g < N_TT) {  // e1 rows: even->text[g], odd->shape[g>>1]
      src = (g & 1) ? (shape + (size_t)(g >> 1) * KD) : (text + (size_t)g * KD);
    } else {         // e2 rows: even->shape[q>>1], odd->text[q]
      int q = g - N_TT;
      src = (q & 1) ? (text + (size_t)q * KD) : (shape + (size_t)(q >> 1) * KD);
    }
    dst = emb + (size_t)g * KD;
    sqp = sq_st + g;
  }
  float s = 0.f;
#pragma unroll
  for (int j = 0; j < 4; ++j) {
    int idx = j * 64 + lane;
    float f = src[idx];
    __bf16 h = (__bf16)f;   // RNE
    dst[idx] = h;
    float fv = (float)h;    // square the ROUNDED value for consistency with MFMA G
    s += fv * fv;
  }
#pragma unroll
  for (int m = 1; m < 64; m <<= 1) s += __shfl_xor(s, m, 64);
  if (lane == 0) *sqp = s;
}

// ---- fused Gram + D + E + masked row-sum kernel (C = X X^T, gemm_bt) -------
__global__ __launch_bounds__(256, 2) void egemm_kernel(const __bf16* __restrict__ X,
                                                       const float* __restrict__ sq,
                                                       float* __restrict__ rowsum,
                                                       int is_st) {
  __shared__ __align__(16) __bf16 As[BM * BK];
  __shared__ __align__(16) __bf16 Bs[BN * BK];

  const int tid = threadIdx.x;
  const int lane = tid & 63;
  const int w = tid >> 6;          // wave 0..3; 2x2 wave grid of 64x64 tiles
  const int warpM = w >> 1, warpN = w & 1;
  const int quad = lane >> 4;
  const int l15 = lane & 15;

  const int mBase = blockIdx.y * BM;
  const int nBase = blockIdx.x * BN;

  floatx4 acc[4][4] = {};

  // staging: lane L covers row L>>2 of a 16-row slab, bytes (L&3)*16
  const int srow = lane >> 2;
  const int scol = (lane & 3) * 8;

  for (int kt = 0; kt < KD; kt += BK) {
    __syncthreads();
#pragma unroll
    for (int t = 0; t < 2; ++t) {
      int ra = t * 64 + w * 16;  // wave-uniform slab base row
      gload_lds16(X + (size_t)(mBase + ra + srow) * KD + kt + scol, &As[ra * BK]);
      gload_lds16(X + (size_t)(nBase + ra + srow) * KD + kt + scol, &Bs[ra * BK]);
    }
    __syncthreads();

    bf16x8 af[4], bfr[4];
#pragma unroll
    for (int tm = 0; tm < 4; ++tm)
      af[tm] = *(const bf16x8*)&As[(warpM * 64 + tm * 16 + l15) * BK + quad * 8];
#pragma unroll
    for (int tn = 0; tn < 4; ++tn)
      bfr[tn] = *(const bf16x8*)&Bs[(warpN * 64 + tn * 16 + l15) * BK + quad * 8];
#pragma unroll
    for (int tm = 0; tm < 4; ++tm)
#pragma unroll
      for (int tn = 0; tn < 4; ++tn)
        acc[tm][tn] = __builtin_amdgcn_mfma_f32_16x16x32_bf16(af[tm], bfr[tn], acc[tm][tn], 0, 0, 0);
  }

  // ---- epilogue: D, E, mask, row-reduce, atomic add ----
  const int rbase = mBase + warpM * 64;
  const int cbase = nBase + warpN * 64;
  float sqr[4][4], sqc[4];
#pragma unroll
  for (int tm = 0; tm < 4; ++tm)
#pragma unroll
    for (int r = 0; r < 4; ++r)
      sqr[tm][r] = sq[rbase + tm * 16 + quad * 4 + r];
#pragma unroll
  for (int tn = 0; tn < 4; ++tn)
    sqc[tn] = sq[cbase + tn * 16 + l15];

#pragma unroll
  for (int tm = 0; tm < 4; ++tm) {
    float rs[4] = {0.f, 0.f, 0.f, 0.f};
#pragma unroll
    for (int tn = 0; tn < 4; ++tn) {
      int col = cbase + tn * 16 + l15;
#pragma unroll
      for (int r = 0; r < 4; ++r) {
        int row = rbase + tm * 16 + quad * 4 + r;  // C/D: row=quad*4+reg, col=lane&15
        float v = acc[tm][tn][r];
        float dsq = sqr[tm][r] + sqc[tn] - 2.0f * v;
        float dst = dsq > 0.f ? sqrtf(dsq) : 0.f;
        float ev = __expf(1.0f - dst);
        if ((row >> 1) == (col >> 1)) ev = 0.f;  // exclude own pair 2x2 block
        if (is_st) {
          // exact duplicate rows: (2s+1, 4096+2s) and transpose -> D=0, E=e
          int d = col - row;
          if ((d == 4095 && (row & 1)) || (d == -4095 && !(row & 1)))
            ev = 2.71828182845904523536f;
        }
        rs[r] += ev;
      }
    }
#pragma unroll
    for (int r = 0; r < 4; ++r) {
      float v = rs[r];
      v += __shfl_xor(v, 1, 64);
      v += __shfl_xor(v, 2, 64);
      v += __shfl_xor(v, 4, 64);
      v += __shfl_xor(v, 8, 64);   // reduce the 16 lanes of this quad (same row)
      if (l15 == 0) atomicAdd(&rowsum[rbase + tm * 16 + quad * 4 + r], v);
    }
  }
}

// ---- final: per-pair fp32 distance + J + loss ------------------------------
__global__ __launch_bounds__(256) void loss_kernel(const float* __restrict__ text,
                                                   const float* __restrict__ shape,
                                                   const float* __restrict__ rowsum_tt,
                                                   const float* __restrict__ rowsum_st,
                                                   float* __restrict__ out) {
  __shared__ float part[4];
  int wv = blockIdx.x * 4 + (threadIdx.x >> 6);  // one wave per pair
  int lane = threadIdx.x & 63;
  const float *a, *b;
  float ns, scale;
  if (wv < P_TT) {
    int p = wv;
    a = text + (size_t)(2 * p) * KD;
    b = text + (size_t)(2 * p + 1) * KD;
    ns = rowsum_tt[2 * p] + rowsum_tt[2 * p + 1];
    scale = 1.0f / (2.0f * P_TT);
  } else {
    int p = wv - P_TT;
    if (p < 2048) {               // emb[2p]=text[2p], emb[2p+1]=shape[p]
      a = text + (size_t)(2 * p) * KD;
      b = shape + (size_t)p * KD;
    } else {                      // emb[2p]=shape[p-2048], emb[2p+1]=text[2(p-2048)+1]
      int s = p - 2048;
      a = shape + (size_t)s * KD;
      b = text + (size_t)(2 * s + 1) * KD;
    }
    ns = rowsum_st[2 * p] + rowsum_st[2 * p + 1];
    scale = 1.0f / (2.0f * P_ST);
  }
  float s = 0.f;
#pragma unroll
  for (int j = 0; j < 4; ++j) {
    int idx = j * 64 + lane;
    float d = a[idx] - b[idx];
    s += d * d;
  }
#pragma unroll
  for (int m = 1; m < 64; m <<= 1) s += __shfl_xor(s, m, 64);
  if (lane == 0) {
    float D = s > 0.f ? sqrtf(s) : 0.f;
    float J = logf(ns) + D;
    part[threadIdx.x >> 6] = (J > 0.f) ? J * J * scale : 0.f;
  }
  __syncthreads();
  if (threadIdx.x == 0)
    atomicAdd(out, part[0] + part[1] + part[2] + part[3]);
}

extern "C" void kernel_launch(void* const* d_in, const int* in_sizes, int n_in,
                              void* d_out, int out_size, void* d_ws, size_t ws_size,
                              hipStream_t stream) {
  const float* text = (const float*)d_in[0];
  const float* shape = (const float*)d_in[1];
  float* out = (float*)d_out;

  char* ws = (char*)d_ws;
  __bf16* xtt = (__bf16*)ws;                                  // 2 MB
  __bf16* emb = (__bf16*)(ws + (size_t)N_TT * KD * 2);        // 4 MB
  float* sq_tt = (float*)(ws + (size_t)6 * 1024 * 1024);      // 16 KB
  float* sq_st = sq_tt + N_TT;                                // 32 KB
  float* rowsum_tt = sq_st + N_ST;                            // 16 KB
  float* rowsum_st = rowsum_tt + N_TT;                        // 32 KB

  hipMemsetAsync(rowsum_tt, 0, (N_TT + N_ST) * sizeof(float), stream);
  hipMemsetAsync(out, 0, (size_t)out_size * sizeof(float), stream);

  prep_kernel<<<(N_TT + N_ST) / 4, 256, 0, stream>>>(text, shape, xtt, emb, sq_tt, sq_st);

  dim3 gtt(N_TT / BN, N_TT / BM);
  egemm_kernel<<<gtt, 256, 0, stream>>>(xtt, sq_tt, rowsum_tt, 0);
  dim3 gst(N_ST / BN, N_ST / BM);
  egemm_kernel<<<gst, 256, 0, stream>>>(emb, sq_st, rowsum_st, 1);

  loss_kernel<<<(P_TT + P_ST) / 4, 256, 0, stream>>>(text, shape, rowsum_tt, rowsum_st, out);
}

// Round 2
// 157.435 us; speedup vs baseline: 1.4483x; 1.4483x over previous
//
#include <hip/hip_runtime.h>
#include <hip/hip_bf16.h>
#include <math.h>

// ---------------------------------------------------------------------------
// Metric loss (lifted structure) on MI355X.
// R2: (1) XOR-swizzled LDS layout -> conflict-free ds_read_b128 fragments
//     (2) triangular grid exploiting E-symmetry (row + col contributions)
//     (3) tt+st fused into one launch; memsets folded into prep; occupancy 4
// ---------------------------------------------------------------------------

typedef __bf16 bf16x8 __attribute__((ext_vector_type(8)));
typedef float floatx4 __attribute__((ext_vector_type(4)));

#define KD 256
#define N_TT 4096
#define N_ST 8192
#define P_TT 2048
#define P_ST 4096
#define BM 128
#define BN 128
#define BK 32
#define NB_TT (N_TT / BM)                /* 32 */
#define NB_ST (N_ST / BM)                /* 64 */
#define T_TT (NB_TT * (NB_TT + 1) / 2)   /* 528 */
#define T_ST (NB_ST * (NB_ST + 1) / 2)   /* 2080 */

// logical (row r, 16B k-slot q) -> bf16 element index in swizzled LDS tile
// phys 16B slot = r*4 + (q ^ ((r>>1)&3)); conflict-free for 16-lane phases.
#define LSLOT(r, q) ((((r) * 4 + ((q) ^ (((r) >> 1) & 3)))) * 8)

__device__ __forceinline__ void gload_lds16(const void* g, void* l) {
  __builtin_amdgcn_global_load_lds((const __attribute__((address_space(1))) unsigned int*)g,
                                   (__attribute__((address_space(3))) unsigned int*)l,
                                   16, 0, 0);
}

// ---- prep: bf16 convert text, build emb, row sq from bf16; zero accums -----
__global__ __launch_bounds__(256) void prep_kernel(const float* __restrict__ text,
                                                   const float* __restrict__ shape,
                                                   __bf16* __restrict__ xtt,
                                                   __bf16* __restrict__ emb,
                                                   float* __restrict__ sq_tt,
                                                   float* __restrict__ sq_st,
                                                   float* __restrict__ rowsum_all,
                                                   float* __restrict__ out, int out_n) {
  int wave = (blockIdx.x * 256 + threadIdx.x) >> 6;  // one wave per output row
  int lane = threadIdx.x & 63;
  if (lane == 0) rowsum_all[wave] = 0.f;             // rowsum_tt ++ rowsum_st contiguous
  if (blockIdx.x == 0 && threadIdx.x == 0)
    for (int i = 0; i < out_n; ++i) out[i] = 0.f;
  const float* src;
  __bf16* dst;
  float* sqp;
  if (wave < N_TT) {
    src = text + (size_t)wave * KD;
    dst = xtt + (size_t)wave * KD;
    sqp = sq_tt + wave;
  } else {
    int g = wave - N_TT;
    if (g < N_TT) {  // e1 rows: even->text[g], odd->shape[g>>1]
      src = (g & 1) ? (shape + (size_t)(g >> 1) * KD) : (text + (size_t)g * KD);
    } else {         // e2 rows: even->shape[q>>1], odd->text[q]
      int q = g - N_TT;
      src = (q & 1) ? (text + (size_t)q * KD) : (shape + (size_t)(q >> 1) * KD);
    }
    dst = emb + (size_t)g * KD;
    sqp = sq_st + g;
  }
  float s = 0.f;
#pragma unroll
  for (int j = 0; j < 4; ++j) {
    int idx = j * 64 + lane;
    float f = src[idx];
    __bf16 h = (__bf16)f;   // RNE
    dst[idx] = h;
    float fv = (float)h;    // square the ROUNDED value for consistency with MFMA G
    s += fv * fv;
  }
#pragma unroll
  for (int m = 1; m < 64; m <<= 1) s += __shfl_xor(s, m, 64);
  if (lane == 0) *sqp = s;
}

// ---- fused triangular Gram + D + E + masked row/col-sum kernel -------------
__global__ __launch_bounds__(256, 4) void egemm_tri_kernel(
    const __bf16* __restrict__ xtt, const __bf16* __restrict__ emb,
    const float* __restrict__ sq_tt, const float* __restrict__ sq_st,
    float* __restrict__ rowsum_tt, float* __restrict__ rowsum_st) {
  __shared__ __align__(16) __bf16 As[BM * BK];
  __shared__ __align__(16) __bf16 Bs[BN * BK];

  int t = blockIdx.x;
  const __bf16* X;
  const float* sq;
  float* rowsum;
  int is_st;
  if (t < T_TT) { X = xtt; sq = sq_tt; rowsum = rowsum_tt; is_st = 0; }
  else { t -= T_TT; X = emb; sq = sq_st; rowsum = rowsum_st; is_st = 1; }

  // triangular decode: by >= bx
  int by = (int)((sqrtf(8.0f * (float)t + 1.0f) - 1.0f) * 0.5f);
  while ((by + 1) * (by + 2) / 2 <= t) ++by;
  while (by * (by + 1) / 2 > t) --by;
  const int bx = t - by * (by + 1) / 2;

  const int mBase = by * BM;  // rows (mBase >= nBase)
  const int nBase = bx * BN;  // cols
  const bool diag = (by == bx);

  const int tid = threadIdx.x;
  const int lane = tid & 63;
  const int w = tid >> 6;  // wave 0..3; 2x2 wave grid of 64x64 tiles
  const int warpM = w >> 1, warpN = w & 1;
  const int quad = lane >> 4;
  const int l15 = lane & 15;

  floatx4 acc[4][4] = {};

  // staging: chunk c (16 rows, 1KB LDS); lane L -> row 16c+(L>>2),
  // k-slot ks = (L&3)^((L>>3)&3)  (global access stays 64B-coalesced,
  // LDS contents land XOR-swizzled per LSLOT)
  const int sRow = lane >> 2;
  const int sCol = (((lane & 3) ^ ((lane >> 3) & 3))) * 8;

  for (int kt = 0; kt < KD; kt += BK) {
    __syncthreads();
#pragma unroll
    for (int h = 0; h < 2; ++h) {
      int c = h * 4 + w;  // chunk 0..7
      gload_lds16(X + (size_t)(mBase + c * 16 + sRow) * KD + kt + sCol, &As[c * 512]);
      gload_lds16(X + (size_t)(nBase + c * 16 + sRow) * KD + kt + sCol, &Bs[c * 512]);
    }
    __syncthreads();

    bf16x8 af[4], bfr[4];
#pragma unroll
    for (int tm = 0; tm < 4; ++tm)
      af[tm] = *(const bf16x8*)&As[LSLOT(warpM * 64 + tm * 16 + l15, quad)];
#pragma unroll
    for (int tn = 0; tn < 4; ++tn)
      bfr[tn] = *(const bf16x8*)&Bs[LSLOT(warpN * 64 + tn * 16 + l15, quad)];
#pragma unroll
    for (int tm = 0; tm < 4; ++tm)
#pragma unroll
      for (int tn = 0; tn < 4; ++tn)
        acc[tm][tn] = __builtin_amdgcn_mfma_f32_16x16x32_bf16(af[tm], bfr[tn], acc[tm][tn], 0, 0, 0);
  }

  // ---- epilogue: D, E, mask, row+col reduce, atomic add ----
  const int rbase = mBase + warpM * 64;
  const int cbase = nBase + warpN * 64;
  float sqr[4][4], sqc[4];
#pragma unroll
  for (int tm = 0; tm < 4; ++tm)
#pragma unroll
    for (int r = 0; r < 4; ++r)
      sqr[tm][r] = sq[rbase + tm * 16 + quad * 4 + r];
#pragma unroll
  for (int tn = 0; tn < 4; ++tn)
    sqc[tn] = sq[cbase + tn * 16 + l15];

  float cs[4] = {0.f, 0.f, 0.f, 0.f};
#pragma unroll
  for (int tm = 0; tm < 4; ++tm) {
    float rs[4] = {0.f, 0.f, 0.f, 0.f};
#pragma unroll
    for (int tn = 0; tn < 4; ++tn) {
      int col = cbase + tn * 16 + l15;
#pragma unroll
      for (int r = 0; r < 4; ++r) {
        int row = rbase + tm * 16 + quad * 4 + r;  // C/D: row=quad*4+reg, col=lane&15
        float v = acc[tm][tn][r];
        float dsq = sqr[tm][r] + sqc[tn] - 2.0f * v;
        float dst = dsq > 0.f ? sqrtf(dsq) : 0.f;
        float ev = __expf(1.0f - dst);
        if ((row >> 1) == (col >> 1)) ev = 0.f;  // own-pair 2x2 block (diag blocks only)
        // exact duplicate rows in emb: (4096+2s, 2s+1), lower triangle -> E=e
        if (is_st && (row - col == 4095) && !(row & 1))
          ev = 2.71828182845904523536f;
        rs[r] += ev;
        cs[tn] += ev;
      }
    }
#pragma unroll
    for (int r = 0; r < 4; ++r) {
      float v = rs[r];
      v += __shfl_xor(v, 1, 64);
      v += __shfl_xor(v, 2, 64);
      v += __shfl_xor(v, 4, 64);
      v += __shfl_xor(v, 8, 64);  // reduce the 16 cols of this quad's row
      if (l15 == 0) atomicAdd(&rowsum[rbase + tm * 16 + quad * 4 + r], v);
    }
  }
  if (!diag) {
    // transpose contribution: column sums -> rowsum[col]
#pragma unroll
    for (int tn = 0; tn < 4; ++tn) {
      float v = cs[tn];
      v += __shfl_xor(v, 16, 64);
      v += __shfl_xor(v, 32, 64);  // reduce over the 4 quads (64 rows total)
      if (quad == 0) atomicAdd(&rowsum[cbase + tn * 16 + l15], v);
    }
  }
}

// ---- final: per-pair fp32 distance + J + loss ------------------------------
__global__ __launch_bounds__(256) void loss_kernel(const float* __restrict__ text,
                                                   const float* __restrict__ shape,
                                                   const float* __restrict__ rowsum_tt,
                                                   const float* __restrict__ rowsum_st,
                                                   float* __restrict__ out) {
  __shared__ float part[4];
  int wv = blockIdx.x * 4 + (threadIdx.x >> 6);  // one wave per pair
  int lane = threadIdx.x & 63;
  const float *a, *b;
  float ns, scale;
  if (wv < P_TT) {
    int p = wv;
    a = text + (size_t)(2 * p) * KD;
    b = text + (size_t)(2 * p + 1) * KD;
    ns = rowsum_tt[2 * p] + rowsum_tt[2 * p + 1];
    scale = 1.0f / (2.0f * P_TT);
  } else {
    int p = wv - P_TT;
    if (p < 2048) {  // emb[2p]=text[2p], emb[2p+1]=shape[p]
      a = text + (size_t)(2 * p) * KD;
      b = shape + (size_t)p * KD;
    } else {         // emb[2p]=shape[p-2048], emb[2p+1]=text[2(p-2048)+1]
      int s = p - 2048;
      a = shape + (size_t)s * KD;
      b = text + (size_t)(2 * s + 1) * KD;
    }
    ns = rowsum_st[2 * p] + rowsum_st[2 * p + 1];
    scale = 1.0f / (2.0f * P_ST);
  }
  float s = 0.f;
#pragma unroll
  for (int j = 0; j < 4; ++j) {
    int idx = j * 64 + lane;
    float d = a[idx] - b[idx];
    s += d * d;
  }
#pragma unroll
  for (int m = 1; m < 64; m <<= 1) s += __shfl_xor(s, m, 64);
  if (lane == 0) {
    float D = s > 0.f ? sqrtf(s) : 0.f;
    float J = logf(ns) + D;
    part[threadIdx.x >> 6] = (J > 0.f) ? J * J * scale : 0.f;
  }
  __syncthreads();
  if (threadIdx.x == 0)
    atomicAdd(out, part[0] + part[1] + part[2] + part[3]);
}

extern "C" void kernel_launch(void* const* d_in, const int* in_sizes, int n_in,
                              void* d_out, int out_size, void* d_ws, size_t ws_size,
                              hipStream_t stream) {
  const float* text = (const float*)d_in[0];
  const float* shape = (const float*)d_in[1];
  float* out = (float*)d_out;

  char* ws = (char*)d_ws;
  __bf16* xtt = (__bf16*)ws;                              // 2 MB
  __bf16* emb = (__bf16*)(ws + (size_t)N_TT * KD * 2);    // 4 MB
  float* sq_tt = (float*)(ws + (size_t)6 * 1024 * 1024);  // 16 KB
  float* sq_st = sq_tt + N_TT;                            // 32 KB
  float* rowsum_tt = sq_st + N_ST;                        // 16 KB  (contiguous with
  float* rowsum_st = rowsum_tt + N_TT;                    // 32 KB   rowsum_st)

  prep_kernel<<<(N_TT + N_ST) / 4, 256, 0, stream>>>(text, shape, xtt, emb, sq_tt, sq_st,
                                                     rowsum_tt, out, out_size);

  egemm_tri_kernel<<<T_TT + T_ST, 256, 0, stream>>>(xtt, emb, sq_tt, sq_st,
                                                    rowsum_tt, rowsum_st);

  loss_kernel<<<(P_TT + P_ST) / 4, 256, 0, stream>>>(text, shape, rowsum_tt, rowsum_st, out);
}

// Round 3
// 99.213 us; speedup vs baseline: 2.2981x; 1.5868x over previous
//
#include <hip/hip_runtime.h>
#include <hip/hip_bf16.h>
#include <math.h>

// ---------------------------------------------------------------------------
// Metric loss (lifted structure) on MI355X.
// R3: single triangular Gram over the 6144 UNIQUE rows (text 4096 + shape
// 2048) with diagonal-free partial sums St (over text cols) / Ss (over shape
// cols). Both losses reconstructed analytically:
//   tt:  ns = St[2p]+St[2p+1] - 2*exp(1-Dp)
//   st:  ns = G(u1)+G(u2) + e - 2*exp(1-Dp),  G = St + 2*Ss
// (pair-E corrections in exact fp32; duplicate-shape D=0 term is the +e).
// LDS-aggregated row/col sums -> 256 atomics/block; loss via partials+reduce.
// ---------------------------------------------------------------------------

typedef __bf16 bf16x8 __attribute__((ext_vector_type(8)));
typedef float floatx4 __attribute__((ext_vector_type(4)));

#define KD 256
#define NU 6144
#define NBU 48
#define TU (NBU * (NBU + 1) / 2) /* 1176 */
#define BM 128
#define BK 32
#define ECONST 2.718281828459045f
#define LOSS_BLOCKS 1536

// logical (row r, 16B k-slot q) -> bf16 element index in swizzled LDS tile
#define LSLOT(r, q) ((((r) * 4 + ((q) ^ (((r) >> 1) & 3)))) * 8)

__device__ __forceinline__ void gload_lds16(const void* g, void* l) {
  __builtin_amdgcn_global_load_lds((const __attribute__((address_space(1))) unsigned int*)g,
                                   (__attribute__((address_space(3))) unsigned int*)l,
                                   16, 0, 0);
}

// ---- prep: bf16 convert unique rows, row sq from bf16; zero accumulators ---
__global__ __launch_bounds__(256) void prep_kernel(const float* __restrict__ text,
                                                   const float* __restrict__ shape,
                                                   __bf16* __restrict__ Xu,
                                                   float* __restrict__ sq,
                                                   float* __restrict__ rowacc) {
  int gt = blockIdx.x * 256 + threadIdx.x;
  if (gt < 2 * NU) rowacc[gt] = 0.f;  // St ++ Ss contiguous
  int wave = gt >> 6;                 // one wave per unique row, 0..6143
  int lane = gt & 63;
  const float* src = (wave < 4096) ? (text + (size_t)wave * KD)
                                   : (shape + (size_t)(wave - 4096) * KD);
  __bf16* dst = Xu + (size_t)wave * KD;
  float s = 0.f;
#pragma unroll
  for (int j = 0; j < 4; ++j) {
    int idx = j * 64 + lane;
    float f = src[idx];
    __bf16 h = (__bf16)f;  // RNE
    dst[idx] = h;
    float fv = (float)h;   // square the ROUNDED value (consistency with MFMA G)
    s += fv * fv;
  }
#pragma unroll
  for (int m = 1; m < 64; m <<= 1) s += __shfl_xor(s, m, 64);
  if (lane == 0) sq[wave] = s;
}

// ---- triangular Gram + E + diag-free row/col partial sums ------------------
__global__ __launch_bounds__(256, 4) void egemm_tri_kernel(
    const __bf16* __restrict__ X, const float* __restrict__ sq,
    float* __restrict__ rowacc) {  // [0,NU)=St, [NU,2NU)=Ss
  __shared__ __align__(16) __bf16 As[BM * BK];
  __shared__ __align__(16) __bf16 Bs[BM * BK];
  __shared__ float rowbuf[2][128];
  __shared__ float colbuf[2][128];

  // triangular decode: by >= bx
  int t = blockIdx.x;
  int by = (int)((sqrtf(8.0f * (float)t + 1.0f) - 1.0f) * 0.5f);
  while ((by + 1) * (by + 2) / 2 <= t) ++by;
  while (by * (by + 1) / 2 > t) --by;
  const int bx = t - by * (by + 1) / 2;

  const int mBase = by * BM;  // rows (mBase >= nBase)
  const int nBase = bx * BM;  // cols
  const bool diag = (by == bx);

  const int tid = threadIdx.x;
  const int lane = tid & 63;
  const int w = tid >> 6;  // 2x2 wave grid of 64x64 tiles
  const int warpM = w >> 1, warpN = w & 1;
  const int quad = lane >> 4;
  const int l15 = lane & 15;

  floatx4 acc[4][4] = {};

  // staging: chunk c (16 rows, 1KB); lane L -> row 16c+(L>>2), swizzled k-slot
  const int sRow = lane >> 2;
  const int sCol = (((lane & 3) ^ ((lane >> 3) & 3))) * 8;

  for (int kt = 0; kt < KD; kt += BK) {
    __syncthreads();
#pragma unroll
    for (int h = 0; h < 2; ++h) {
      int c = h * 4 + w;
      gload_lds16(X + (size_t)(mBase + c * 16 + sRow) * KD + kt + sCol, &As[c * 512]);
      gload_lds16(X + (size_t)(nBase + c * 16 + sRow) * KD + kt + sCol, &Bs[c * 512]);
    }
    __syncthreads();

    bf16x8 af[4], bfr[4];
#pragma unroll
    for (int tm = 0; tm < 4; ++tm)
      af[tm] = *(const bf16x8*)&As[LSLOT(warpM * 64 + tm * 16 + l15, quad)];
#pragma unroll
    for (int tn = 0; tn < 4; ++tn)
      bfr[tn] = *(const bf16x8*)&Bs[LSLOT(warpN * 64 + tn * 16 + l15, quad)];
#pragma unroll
    for (int tm = 0; tm < 4; ++tm)
#pragma unroll
      for (int tn = 0; tn < 4; ++tn)
        acc[tm][tn] = __builtin_amdgcn_mfma_f32_16x16x32_bf16(af[tm], bfr[tn], acc[tm][tn], 0, 0, 0);
  }

  // ---- epilogue: E = exp(1-D), diag-free row+col sums ----
  const int rbase = mBase + warpM * 64;
  const int cbase = nBase + warpN * 64;
  float sqr[4][4], sqc[4];
#pragma unroll
  for (int tm = 0; tm < 4; ++tm)
#pragma unroll
    for (int r = 0; r < 4; ++r)
      sqr[tm][r] = sq[rbase + tm * 16 + quad * 4 + r];
#pragma unroll
  for (int tn = 0; tn < 4; ++tn)
    sqc[tn] = sq[cbase + tn * 16 + l15];

  const float L2E = 1.44269504088896f;
  float cs[4] = {0.f, 0.f, 0.f, 0.f};
#pragma unroll
  for (int tm = 0; tm < 4; ++tm) {
    float rs[4] = {0.f, 0.f, 0.f, 0.f};
#pragma unroll
    for (int tn = 0; tn < 4; ++tn) {
#pragma unroll
      for (int r = 0; r < 4; ++r) {
        float v = acc[tm][tn][r];
        float dsq = fmaf(-2.0f, v, sqr[tm][r] + sqc[tn]);
        float dst = sqrtf(fmaxf(dsq, 0.f));
        float ev = __builtin_amdgcn_exp2f(fmaf(-L2E, dst, L2E));
        // unique-level diagonal excluded (handled analytically downstream)
        if (diag && tm == tn && (quad * 4 + r) == l15) ev = 0.f;
        rs[r] += ev;
        cs[tn] += ev;
      }
    }
#pragma unroll
    for (int r = 0; r < 4; ++r) {
      float v = rs[r];
      v += __shfl_xor(v, 1, 64);
      v += __shfl_xor(v, 2, 64);
      v += __shfl_xor(v, 4, 64);
      v += __shfl_xor(v, 8, 64);
      if (l15 == 0) rowbuf[warpN][warpM * 64 + tm * 16 + quad * 4 + r] = v;
    }
  }
#pragma unroll
  for (int tn = 0; tn < 4; ++tn) {
    float v = cs[tn];
    v += __shfl_xor(v, 16, 64);
    v += __shfl_xor(v, 32, 64);
    if (quad == 0) colbuf[warpM][warpN * 64 + tn * 16 + l15] = v;
  }
  __syncthreads();

  // rows -> St if cols are text (bx<32) else Ss; cols -> St if rows text
  float* rdst = rowacc + (bx < 32 ? 0 : NU);
  float* cdst = rowacc + (by < 32 ? 0 : NU);
  if (tid < 128) {
    atomicAdd(&rdst[mBase + tid], rowbuf[0][tid] + rowbuf[1][tid]);
  } else if (!diag) {
    int c = tid - 128;
    atomicAdd(&cdst[nBase + c], colbuf[0][c] + colbuf[1][c]);
  }
}

// ---- per-pair fp32 distance + analytic ns + J; block partials --------------
__global__ __launch_bounds__(256) void loss_kernel(const float* __restrict__ text,
                                                   const float* __restrict__ shape,
                                                   const float* __restrict__ rowacc,
                                                   float* __restrict__ partials) {
  __shared__ float part[4];
  const float* St = rowacc;
  const float* Ss = rowacc + NU;
  int wv = blockIdx.x * 4 + (threadIdx.x >> 6);  // one wave per pair, 0..6143
  int lane = threadIdx.x & 63;
  const float *a, *b;
  float base, scale;
  if (wv < 2048) {  // tt pair p
    int p = wv;
    a = text + (size_t)(2 * p) * KD;
    b = text + (size_t)(2 * p + 1) * KD;
    base = St[2 * p] + St[2 * p + 1];
    scale = 1.0f / 4096.0f;
  } else {  // st pair
    int p = wv - 2048;
    int u1, u2;
    if (p < 2048) {  // (text_2p, shape_p)
      u1 = 2 * p; u2 = 4096 + p;
      a = text + (size_t)(2 * p) * KD;
      b = shape + (size_t)p * KD;
    } else {         // (shape_s, text_{2s+1})
      int s = p - 2048;
      u1 = 4096 + s; u2 = 2 * s + 1;
      a = shape + (size_t)s * KD;
      b = text + (size_t)(2 * s + 1) * KD;
    }
    float g1 = St[u1] + 2.0f * Ss[u1];
    float g2 = St[u2] + 2.0f * Ss[u2];
    base = g1 + g2 + ECONST;
    scale = 1.0f / 8192.0f;
  }
  float s = 0.f;
#pragma unroll
  for (int j = 0; j < 4; ++j) {
    int idx = j * 64 + lane;
    float d = a[idx] - b[idx];
    s += d * d;
  }
#pragma unroll
  for (int m = 1; m < 64; m <<= 1) s += __shfl_xor(s, m, 64);
  if (lane == 0) {
    float D = s > 0.f ? sqrtf(s) : 0.f;
    float ns = base - 2.0f * expf(1.0f - D);
    float J = logf(ns) + D;
    part[threadIdx.x >> 6] = (J > 0.f) ? J * J * scale : 0.f;
  }
  __syncthreads();
  if (threadIdx.x == 0)
    partials[blockIdx.x] = part[0] + part[1] + part[2] + part[3];
}

// ---- final: sum partials -> out[0] ----------------------------------------
__global__ __launch_bounds__(256) void reduce_kernel(const float* __restrict__ partials,
                                                     float* __restrict__ out, int out_n) {
  __shared__ float part[4];
  float s = 0.f;
  for (int i = threadIdx.x; i < LOSS_BLOCKS; i += 256) s += partials[i];
#pragma unroll
  for (int m = 1; m < 64; m <<= 1) s += __shfl_xor(s, m, 64);
  if ((threadIdx.x & 63) == 0) part[threadIdx.x >> 6] = s;
  __syncthreads();
  if (threadIdx.x == 0) out[0] = part[0] + part[1] + part[2] + part[3];
  else if (threadIdx.x < out_n) out[threadIdx.x] = 0.f;
}

extern "C" void kernel_launch(void* const* d_in, const int* in_sizes, int n_in,
                              void* d_out, int out_size, void* d_ws, size_t ws_size,
                              hipStream_t stream) {
  const float* text = (const float*)d_in[0];
  const float* shape = (const float*)d_in[1];
  float* out = (float*)d_out;

  char* ws = (char*)d_ws;
  __bf16* Xu = (__bf16*)ws;                                // 3 MB
  float* sq = (float*)(ws + (size_t)NU * KD * 2);          // 24 KB
  float* rowacc = sq + NU;                                 // 48 KB (St ++ Ss)
  float* partials = rowacc + 2 * NU;                       // 6 KB

  prep_kernel<<<NU / 4, 256, 0, stream>>>(text, shape, Xu, sq, rowacc);
  egemm_tri_kernel<<<TU, 256, 0, stream>>>(Xu, sq, rowacc);
  loss_kernel<<<LOSS_BLOCKS, 256, 0, stream>>>(text, shape, rowacc, partials);
  reduce_kernel<<<1, 256, 0, stream>>>(partials, out, out_size);
}